// Round 6
// baseline (996.404 us; speedup 1.0000x reference)
//
#include <hip/hip_runtime.h>
#include <math.h>

#define NPTS 4096
#define DIM  32
#define MAXSLOTS 50
#define NTHREADS 256
#define ITHREADS 512
#define NELEM 131072      // 4096*32

// ws layout in floats
#define WS_N2X   0
#define WS_N2Y   4096
#define WS_PMIN  8192
#define WS_PMAX  10240
#define WS_EPS   12288
#define WS_MODE  12352
#define WS_DUAL  12416
#define DUALSZ   16384    // 4 arrays * 4096 (one parity buffer)
#define WS_BF    45184    // fp16 pack area: 2*131072 ushorts = 512 KB

// modes
#define M_SKIP   0
#define M_INIT   1
#define M_AVG    2
#define M_ASSIGN 3

typedef short   short8 __attribute__((ext_vector_type(8)));
typedef _Float16 half8 __attribute__((ext_vector_type(8)));
typedef float   f32x4  __attribute__((ext_vector_type(4)));

__device__ __forceinline__ float exp2fast(float a){
#if __has_builtin(__builtin_amdgcn_exp2f)
    return __builtin_amdgcn_exp2f(a);
#else
    return exp2f(a);
#endif
}
__device__ __forceinline__ float log2fast(float a){
#if __has_builtin(__builtin_amdgcn_logf)
    return __builtin_amdgcn_logf(a);
#else
    return log2f(a);
#endif
}

// ---------------- norms: 0.5*|row|^2 for x and y (exact fp32)
__global__ void sink_norms(const float* __restrict__ x, const float* __restrict__ y,
                           float* __restrict__ ws)
{
    int row = blockIdx.x * blockDim.x + threadIdx.x;   // 32 blocks * 256 = 8192
    const float* src = (row < NPTS) ? (x + (size_t)row * DIM)
                                    : (y + (size_t)(row - NPTS) * DIM);
    const float4* s4 = (const float4*)src;
    float acc = 0.f;
#pragma unroll
    for (int q = 0; q < 8; q++) {
        float4 v = s4[q];
        acc += v.x*v.x + v.y*v.y + v.z*v.z + v.w*v.w;
    }
    ws[row] = 0.5f * acc;
}

// ---------------- fp16 prepack (B-side): [xh | yh] row-major, unscaled
__global__ void sink_prep(const float* __restrict__ x, const float* __restrict__ y,
                          unsigned short* __restrict__ bf)
{
    int tid = blockIdx.x * 256 + threadIdx.x;          // 32768 threads, 8 elems each
    int e = tid * 8;
    const float* src = (e < NELEM) ? (x + e) : (y + (e - NELEM));
    float4 v0 = ((const float4*)src)[0];
    float4 v1 = ((const float4*)src)[1];
    float vs[8] = {v0.x, v0.y, v0.z, v0.w, v1.x, v1.y, v1.z, v1.w};
    short hv[8];
#pragma unroll
    for (int i = 0; i < 8; i++) {
        union { _Float16 f; short s; } u;
        u.f = (_Float16)vs[i];           // RNE f32->f16
        hv[i] = u.s;
    }
    short8 hvec = {hv[0],hv[1],hv[2],hv[3],hv[4],hv[5],hv[6],hv[7]};
    *(short8*)((short*)bf + e) = hvec;   // x at [0,NELEM), y at [NELEM,2*NELEM)
}

// ---------------- per-dim min/max partials over concat(x,y)
__global__ void sink_minmax(const float* __restrict__ x, const float* __restrict__ y,
                            float* __restrict__ ws)
{
    __shared__ float2 mm[8][32];
    int t = threadIdx.x;
    int d = t & 31, rg = t >> 5;
    float mn = 3.4e38f, mx = -3.4e38f;
#pragma unroll
    for (int k = 0; k < 16; k++) {
        int row = blockIdx.x * 128 + k * 8 + rg;
        const float* src = (row < NPTS) ? (x + (size_t)row * DIM)
                                        : (y + (size_t)(row - NPTS) * DIM);
        float v = src[d];
        mn = fminf(mn, v); mx = fmaxf(mx, v);
    }
    mm[rg][d] = make_float2(mn, mx);
    __syncthreads();
    if (t < 32) {
        float2 a = mm[0][t];
#pragma unroll
        for (int g = 1; g < 8; g++) {
            float2 b = mm[g][t];
            a.x = fminf(a.x, b.x); a.y = fmaxf(a.y, b.y);
        }
        ws[WS_PMIN + blockIdx.x * 32 + t] = a.x;
        ws[WS_PMAX + blockIdx.x * 32 + t] = a.y;
    }
}

// ---------------- schedule: diameter -> eps list + mode per slot
__global__ void sink_sched(float* __restrict__ ws)
{
    __shared__ float mins[32], maxs[32];
    int t = threadIdx.x;
    if (t < 32) {
        float mn = 3.4e38f, mx = -3.4e38f;
        for (int b = 0; b < 64; b++) {
            mn = fminf(mn, ws[WS_PMIN + b * 32 + t]);
            mx = fmaxf(mx, ws[WS_PMAX + b * 32 + t]);
        }
        mins[t] = mn; maxs[t] = mx;
    }
    __syncthreads();
    if (t == 0) {
        float dia2 = 0.f;
        for (int d = 0; d < 32; d++) {
            float df = maxs[d] - mins[d];
            dia2 += df * df;
        }
        float dia = sqrtf(dia2);
        float* eps = ws + WS_EPS;
        int*  mode = (int*)(ws + WS_MODE);
        double ld    = log((double)dia);
        double start = 2.0 * ld;
        double stop  = 2.0 * log(0.5);
        double step  = 2.0 * log(0.9);
        int K = (int)ceil((stop - start) / step);
        if (K < 0) K = 0;
        if (K > MAXSLOTS - 5) K = MAXSLOTS - 5;
        eps[0] = dia * dia; mode[0] = M_INIT;
        eps[1] = dia * dia; mode[1] = M_AVG;
        for (int k = 0; k < K; k++) {
            eps[2 + k] = (float)exp(start + step * (double)k);
            mode[2 + k] = M_AVG;
        }
        eps[2 + K] = 0.25f; mode[2 + K] = M_AVG;
        eps[3 + K] = 0.25f; mode[3 + K] = M_ASSIGN;
        for (int s = 4 + K; s < MAXSLOTS; s++) { eps[s] = 0.25f; mode[s] = M_SKIP; }
    }
}

// grouped online-LSE over 4 accumulated cts; ca values are already v = dot*ie2 + hp
#define GLSE(T, R) \
    { float v0 = ca##T[0][R]; \
      float v1 = ca##T[1][R]; \
      float v2 = ca##T[2][R]; \
      float v3 = ca##T[3][R]; \
      float gm = fmaxf(fmaxf(v0, v1), fmaxf(v2, v3)); \
      float nm = fmaxf(ms##T[R], gm); \
      float er = exp2fast(ms##T[R] - nm); \
      float e0 = exp2fast(v0 - nm); \
      float e1 = exp2fast(v1 - nm); \
      float e2 = exp2fast(v2 - nm); \
      float e3 = exp2fast(v3 - nm); \
      ss##T[R] = fmaf(ss##T[R], er, (e0 + e1) + (e2 + e3)); \
      ms##T[R] = nm; }

// ---------------- fused softmin iteration (fp16 MFMA, hp in C-operand, ie2 in A)
// grid = 4 matrices * 128 row-tiles(32 rows) = 512 blocks, 512 threads (8 waves)
// block: 32 rows (2 MFMA row-tiles per wave); wave w: cols [w*512,(w+1)*512)
// column sweep skewed per block to de-phase the shared B stream in L2
__global__ __launch_bounds__(ITHREADS, 4) void sink_iter(
    const float* __restrict__ xg, const float* __restrict__ yg,
    float* __restrict__ ws, int slot)
{
    const int t = threadIdx.x;
    const int mode = ((const int*)(ws + WS_MODE))[slot];

    if (mode == M_SKIP) {
        int idx = blockIdx.x * ITHREADS + t;
        if (idx < DUALSZ)
            ws[WS_DUAL + ((slot + 1) & 1) * DUALSZ + idx] =
                ws[WS_DUAL + (slot & 1) * DUALSZ + idx];
        return;
    }

    const float eps     = ws[WS_EPS + slot];
    const float inv_eps = 1.0f / eps;
    const float L2E     = 1.4426950408889634f;
    const float LN2     = 0.6931471805599453f;
    const float ie2     = inv_eps * L2E;
    const float hbase   = -8.317766166719343f;   // -ln(4096)
    const float don     = (mode == M_INIT) ? 0.0f : 1.0f;

    const int bm   = blockIdx.x >> 7;     // 0=xy 1=yx 2=xx 3=yy
    const int tile = blockIdx.x & 127;    // 32-row tile index
    const int S    = (blockIdx.x * 5) & 31;   // per-block sweep skew
    const int rowIsX = (bm == 0 || bm == 2);
    const int colIsX = (bm == 1 || bm == 2);

    const short* bf = (const short*)(ws + WS_BF);
    const float* rsrcf = rowIsX ? xg : yg;          // fp32 A-side source
    const short* cbase = bf + (colIsX ? 0 : NELEM); // fp16 B-side source
    const float* rn2 = ws + (rowIsX ? WS_N2X : WS_N2Y);
    const float* cn2 = ws + (colIsX ? WS_N2X : WS_N2Y);

    const float* bufold = ws + WS_DUAL + (slot & 1) * DUALSZ;
    float*       bufnew = ws + WS_DUAL + ((slot + 1) & 1) * DUALSZ;
    const int dualsel = (bm == 0) ? 1 : (bm == 1) ? 0 : bm;   // {1,0,2,3}
    const float* dual   = bufold + dualsel * NPTS;
    const float* oldout = bufold + bm * NPTS;
    float*       out    = bufnew + bm * NPTS;

    __shared__ float  hps[NPTS];          // 16 KB
    __shared__ float2 parts[8][32];       // 2 KB

    const int lane = t & 63;
    const int wv   = t >> 6;
    const int lr   = lane & 15;          // A-row / B-col within 16-tile
    const int lk   = (lane >> 4) * 8;    // k offset (8 contiguous fp16)

    // A fragments: fp32 rows scaled by ie2, converted to fp16 in-kernel
    const int ar0 = tile * 32 + lr;
    half8 a0s, a1s;
    {
        const float4 p0 = *(const float4*)(rsrcf + (size_t)ar0 * DIM + lk);
        const float4 p1 = *(const float4*)(rsrcf + (size_t)ar0 * DIM + lk + 4);
        const float4 q0 = *(const float4*)(rsrcf + (size_t)(ar0 + 16) * DIM + lk);
        const float4 q1 = *(const float4*)(rsrcf + (size_t)(ar0 + 16) * DIM + lk + 4);
        a0s[0] = (_Float16)(p0.x * ie2); a0s[1] = (_Float16)(p0.y * ie2);
        a0s[2] = (_Float16)(p0.z * ie2); a0s[3] = (_Float16)(p0.w * ie2);
        a0s[4] = (_Float16)(p1.x * ie2); a0s[5] = (_Float16)(p1.y * ie2);
        a0s[6] = (_Float16)(p1.z * ie2); a0s[7] = (_Float16)(p1.w * ie2);
        a1s[0] = (_Float16)(q0.x * ie2); a1s[1] = (_Float16)(q0.y * ie2);
        a1s[2] = (_Float16)(q0.z * ie2); a1s[3] = (_Float16)(q0.w * ie2);
        a1s[4] = (_Float16)(q1.x * ie2); a1s[5] = (_Float16)(q1.y * ie2);
        a1s[6] = (_Float16)(q1.z * ie2); a1s[7] = (_Float16)(q1.w * ie2);
    }

    // build hp[j] for all 4096 cols (coalesced)
#pragma unroll
    for (int q = 0; q < 8; q++) {
        int j = t + q * ITHREADS;
        hps[j] = (hbase + fmaf(don, dual[j], -cn2[j]) * inv_eps) * L2E;
    }
    __syncthreads();

    // wave's column window + depth-4 rings for B fragments and hp
    const int colbase = wv * 512;
    const short* cwb = cbase + (size_t)colbase * DIM;
    const int laneoff = lr * DIM + lk;
    const float* hpw = hps + colbase + lr;

    half8 bh[4];
    float hpv[4];
#pragma unroll
    for (int p = 0; p < 4; p++) {
        const int w = (p + S) & 31;
        bh[p]  = *(const half8*)(cwb + w * (16 * DIM) + laneoff);
        hpv[p] = hpw[w * 16];
    }

    float ms0[4] = {-INFINITY, -INFINITY, -INFINITY, -INFINITY};
    float ms1[4] = {-INFINITY, -INFINITY, -INFINITY, -INFINITY};
    float ss0[4] = {0.f, 0.f, 0.f, 0.f};
    float ss1[4] = {0.f, 0.f, 0.f, 0.f};

    f32x4 ca0[4], ca1[4];

#pragma unroll
    for (int ct = 0; ct < 32; ct++) {
        const int sl = ct & 3;
        const half8 hB = bh[sl];
        const float hp = hpv[sl];
        f32x4 u0 = {hp, hp, hp, hp};
        f32x4 u1 = {hp, hp, hp, hp};
        u0 = __builtin_amdgcn_mfma_f32_16x16x32_f16(a0s, hB, u0, 0, 0, 0);
        u1 = __builtin_amdgcn_mfma_f32_16x16x32_f16(a1s, hB, u1, 0, 0, 0);
        if (ct < 28) {
            const int w = ((ct + 4) + S) & 31;
            bh[sl]  = *(const half8*)(cwb + w * (16 * DIM) + laneoff);
            hpv[sl] = hpw[w * 16];
        }
        ca0[sl] = u0;
        ca1[sl] = u1;
        if (sl == 3) {
            GLSE(0, 0) GLSE(0, 1) GLSE(0, 2) GLSE(0, 3)
            GLSE(1, 0) GLSE(1, 1) GLSE(1, 2) GLSE(1, 3)
        }
    }

    // merge the 16 col-lanes (lane bits 0..3)
#pragma unroll
    for (int wm = 1; wm <= 8; wm <<= 1) {
#pragma unroll
        for (int r = 0; r < 4; r++) {
            float om, os, nm;
            om = __shfl_xor(ms0[r], wm, 64); os = __shfl_xor(ss0[r], wm, 64);
            nm = fmaxf(ms0[r], om);
            ss0[r] = fmaf(ss0[r], exp2fast(ms0[r] - nm), os * exp2fast(om - nm));
            ms0[r] = nm;
            om = __shfl_xor(ms1[r], wm, 64); os = __shfl_xor(ss1[r], wm, 64);
            nm = fmaxf(ms1[r], om);
            ss1[r] = fmaf(ss1[r], exp2fast(ms1[r] - nm), os * exp2fast(om - nm));
            ms1[r] = nm;
        }
    }
    if (lr == 0) {
        const int g4 = (lane >> 4) * 4;
#pragma unroll
        for (int r = 0; r < 4; r++) {
            parts[wv][g4 + r]      = make_float2(ms0[r], ss0[r]);
            parts[wv][16 + g4 + r] = make_float2(ms1[r], ss1[r]);
        }
    }
    __syncthreads();
    if (t < 32) {
        float2 p = parts[0][t];
        float m = p.x, s = p.y;
#pragma unroll
        for (int w2 = 1; w2 < 8; w2++) {
            float2 q = parts[w2][t];
            float nm = fmaxf(m, q.x);
            s = fmaf(s, exp2fast(m - nm), q.y * exp2fast(q.x - nm));
            m = nm;
        }
        const float lse = LN2 * (m + log2fast(s));
        const int row = tile * 32 + t;
        const float ft = rn2[row] - eps * lse;
        out[row] = (mode == M_AVG) ? 0.5f * (oldout[row] + ft) : ft;
    }
}

// ---------------- final: mean(f_ba - f_aa) + mean(g_ab - g_bb)
__global__ void sink_reduce(const float* __restrict__ ws, float* __restrict__ outp)
{
    __shared__ float red[NTHREADS];
    const float* b = ws + WS_DUAL;   // parity 0 after 50 slots
    int t = threadIdx.x;
    float acc = 0.f;
    for (int i = t; i < NPTS; i += NTHREADS)
        acc += (b[i] - b[2 * NPTS + i]) + (b[NPTS + i] - b[3 * NPTS + i]);
    red[t] = acc;
    __syncthreads();
    for (int s = NTHREADS / 2; s > 0; s >>= 1) {
        if (t < s) red[t] += red[t + s];
        __syncthreads();
    }
    if (t == 0) outp[0] = red[0] * (1.0f / (float)NPTS);
}

extern "C" void kernel_launch(void* const* d_in, const int* in_sizes, int n_in,
                              void* d_out, int out_size, void* d_ws, size_t ws_size,
                              hipStream_t stream)
{
    const float* x = (const float*)d_in[0];
    const float* y = (const float*)d_in[1];
    float* ws  = (float*)d_ws;
    float* out = (float*)d_out;

    hipLaunchKernelGGL(sink_norms,  dim3(32),  dim3(NTHREADS), 0, stream, x, y, ws);
    hipLaunchKernelGGL(sink_prep,   dim3(128), dim3(NTHREADS), 0, stream, x, y,
                       (unsigned short*)(ws + WS_BF));
    hipLaunchKernelGGL(sink_minmax, dim3(64),  dim3(NTHREADS), 0, stream, x, y, ws);
    hipLaunchKernelGGL(sink_sched,  dim3(1),   dim3(NTHREADS), 0, stream, ws);
    for (int s = 0; s < MAXSLOTS; s++)
        hipLaunchKernelGGL(sink_iter, dim3(512), dim3(ITHREADS), 0, stream, x, y, ws, s);
    hipLaunchKernelGGL(sink_reduce, dim3(1), dim3(NTHREADS), 0, stream, ws, out);
}

// Round 7
// 993.369 us; speedup vs baseline: 1.0031x; 1.0031x over previous
//
#include <hip/hip_runtime.h>
#include <math.h>

#define NPTS 4096
#define DIM  32
#define MAXSLOTS 50
#define NTHREADS 256
#define ITHREADS 512
#define NELEM 131072      // 4096*32

// ws layout in floats
#define WS_N2X   0
#define WS_N2Y   4096
#define WS_PMIN  8192
#define WS_PMAX  10240
#define WS_EPS   12288
#define WS_MODE  12352
#define WS_DUAL  12416
#define DUALSZ   16384    // 4 arrays * 4096 (one parity buffer)
#define WS_BF    45184    // fp16 pack area: 2*131072 ushorts = 512 KB

// modes
#define M_SKIP   0
#define M_INIT   1
#define M_AVG    2
#define M_ASSIGN 3

typedef short   short8 __attribute__((ext_vector_type(8)));
typedef _Float16 half8 __attribute__((ext_vector_type(8)));
typedef float   f32x4  __attribute__((ext_vector_type(4)));

__device__ __forceinline__ float exp2fast(float a){
#if __has_builtin(__builtin_amdgcn_exp2f)
    return __builtin_amdgcn_exp2f(a);
#else
    return exp2f(a);
#endif
}
__device__ __forceinline__ float log2fast(float a){
#if __has_builtin(__builtin_amdgcn_logf)
    return __builtin_amdgcn_logf(a);
#else
    return log2f(a);
#endif
}

// ---------------- norms: 0.5*|row|^2 for x and y (exact fp32)
__global__ void sink_norms(const float* __restrict__ x, const float* __restrict__ y,
                           float* __restrict__ ws)
{
    int row = blockIdx.x * blockDim.x + threadIdx.x;   // 32 blocks * 256 = 8192
    const float* src = (row < NPTS) ? (x + (size_t)row * DIM)
                                    : (y + (size_t)(row - NPTS) * DIM);
    const float4* s4 = (const float4*)src;
    float acc = 0.f;
#pragma unroll
    for (int q = 0; q < 8; q++) {
        float4 v = s4[q];
        acc += v.x*v.x + v.y*v.y + v.z*v.z + v.w*v.w;
    }
    ws[row] = 0.5f * acc;
}

// ---------------- fp16 prepack: [xh | yh] row-major
__global__ void sink_prep(const float* __restrict__ x, const float* __restrict__ y,
                          unsigned short* __restrict__ bf)
{
    int tid = blockIdx.x * 256 + threadIdx.x;          // 32768 threads, 8 elems each
    int e = tid * 8;
    const float* src = (e < NELEM) ? (x + e) : (y + (e - NELEM));
    float4 v0 = ((const float4*)src)[0];
    float4 v1 = ((const float4*)src)[1];
    float vs[8] = {v0.x, v0.y, v0.z, v0.w, v1.x, v1.y, v1.z, v1.w};
    short hv[8];
#pragma unroll
    for (int i = 0; i < 8; i++) {
        union { _Float16 f; short s; } u;
        u.f = (_Float16)vs[i];           // RNE f32->f16
        hv[i] = u.s;
    }
    short8 hvec = {hv[0],hv[1],hv[2],hv[3],hv[4],hv[5],hv[6],hv[7]};
    *(short8*)((short*)bf + e) = hvec;   // x at [0,NELEM), y at [NELEM,2*NELEM)
}

// ---------------- per-dim min/max partials over concat(x,y)
__global__ void sink_minmax(const float* __restrict__ x, const float* __restrict__ y,
                            float* __restrict__ ws)
{
    __shared__ float2 mm[8][32];
    int t = threadIdx.x;
    int d = t & 31, rg = t >> 5;
    float mn = 3.4e38f, mx = -3.4e38f;
#pragma unroll
    for (int k = 0; k < 16; k++) {
        int row = blockIdx.x * 128 + k * 8 + rg;
        const float* src = (row < NPTS) ? (x + (size_t)row * DIM)
                                        : (y + (size_t)(row - NPTS) * DIM);
        float v = src[d];
        mn = fminf(mn, v); mx = fmaxf(mx, v);
    }
    mm[rg][d] = make_float2(mn, mx);
    __syncthreads();
    if (t < 32) {
        float2 a = mm[0][t];
#pragma unroll
        for (int g = 1; g < 8; g++) {
            float2 b = mm[g][t];
            a.x = fminf(a.x, b.x); a.y = fmaxf(a.y, b.y);
        }
        ws[WS_PMIN + blockIdx.x * 32 + t] = a.x;
        ws[WS_PMAX + blockIdx.x * 32 + t] = a.y;
    }
}

// ---------------- schedule: diameter -> eps list + mode per slot
__global__ void sink_sched(float* __restrict__ ws)
{
    __shared__ float mins[32], maxs[32];
    int t = threadIdx.x;
    if (t < 32) {
        float mn = 3.4e38f, mx = -3.4e38f;
        for (int b = 0; b < 64; b++) {
            mn = fminf(mn, ws[WS_PMIN + b * 32 + t]);
            mx = fmaxf(mx, ws[WS_PMAX + b * 32 + t]);
        }
        mins[t] = mn; maxs[t] = mx;
    }
    __syncthreads();
    if (t == 0) {
        float dia2 = 0.f;
        for (int d = 0; d < 32; d++) {
            float df = maxs[d] - mins[d];
            dia2 += df * df;
        }
        float dia = sqrtf(dia2);
        float* eps = ws + WS_EPS;
        int*  mode = (int*)(ws + WS_MODE);
        double ld    = log((double)dia);
        double start = 2.0 * ld;
        double stop  = 2.0 * log(0.5);
        double step  = 2.0 * log(0.9);
        int K = (int)ceil((stop - start) / step);
        if (K < 0) K = 0;
        if (K > MAXSLOTS - 5) K = MAXSLOTS - 5;
        eps[0] = dia * dia; mode[0] = M_INIT;
        eps[1] = dia * dia; mode[1] = M_AVG;
        for (int k = 0; k < K; k++) {
            eps[2 + k] = (float)exp(start + step * (double)k);
            mode[2 + k] = M_AVG;
        }
        eps[2 + K] = 0.25f; mode[2 + K] = M_AVG;
        eps[3 + K] = 0.25f; mode[3 + K] = M_ASSIGN;
        for (int s = 4 + K; s < MAXSLOTS; s++) { eps[s] = 0.25f; mode[s] = M_SKIP; }
    }
}

// ---------------- fused softmin iteration (fp16 MFMA, 1 tile/wave, defer-max LSE)
// grid = 4 matrices * 128 row-tiles(32 rows) = 512 blocks, 512 threads (8 waves)
// wave w: row-half (w>>2), col window (w&3)*1024 (64 cts of 16 cols)
// twin waves (w, w^4) share a B window -> L1 reuse; per-block skew de-phases L2
__global__ __launch_bounds__(ITHREADS, 6) void sink_iter(float* __restrict__ ws, int slot)
{
    const int t = threadIdx.x;
    const int mode = ((const int*)(ws + WS_MODE))[slot];

    if (mode == M_SKIP) {
        int idx = blockIdx.x * ITHREADS + t;
        if (idx < DUALSZ)
            ws[WS_DUAL + ((slot + 1) & 1) * DUALSZ + idx] =
                ws[WS_DUAL + (slot & 1) * DUALSZ + idx];
        return;
    }

    const float eps     = ws[WS_EPS + slot];
    const float inv_eps = 1.0f / eps;
    const float L2E     = 1.4426950408889634f;
    const float LN2     = 0.6931471805599453f;
    const float ie2     = inv_eps * L2E;
    const float hbase   = -8.317766166719343f;   // -ln(4096)
    const float don     = (mode == M_INIT) ? 0.0f : 1.0f;

    const int bm   = blockIdx.x >> 7;     // 0=xy 1=yx 2=xx 3=yy
    const int tile = blockIdx.x & 127;    // 32-row tile index
    const int S    = (blockIdx.x * 11) & 63;  // per-block sweep skew over 64 windows
    const int rowIsX = (bm == 0 || bm == 2);
    const int colIsX = (bm == 1 || bm == 2);

    const short* bf = (const short*)(ws + WS_BF);
    const short* rbase = bf + (rowIsX ? 0 : NELEM);
    const short* cbase = bf + (colIsX ? 0 : NELEM);
    const float* rn2 = ws + (rowIsX ? WS_N2X : WS_N2Y);
    const float* cn2 = ws + (colIsX ? WS_N2X : WS_N2Y);

    const float* bufold = ws + WS_DUAL + (slot & 1) * DUALSZ;
    float*       bufnew = ws + WS_DUAL + ((slot + 1) & 1) * DUALSZ;
    const int dualsel = (bm == 0) ? 1 : (bm == 1) ? 0 : bm;   // {1,0,2,3}
    const float* dual   = bufold + dualsel * NPTS;
    const float* oldout = bufold + bm * NPTS;
    float*       out    = bufnew + bm * NPTS;

    __shared__ float  hps[NPTS];          // 16 KB
    __shared__ float2 parts[8][16];       // 1 KB

    const int lane = t & 63;
    const int wv   = t >> 6;
    const int lr   = lane & 15;          // A-row / B-col within 16-tile
    const int lk   = (lane >> 4) * 8;    // k offset (8 contiguous fp16)

    const int tsel = wv >> 2;            // which 16-row half of the 32-row tile
    const int cwin = (wv & 3) << 10;     // column window base (0..3072)

    // A fragment: one row-tile
    const int ar = tile * 32 + tsel * 16 + lr;
    const half8 a0 = *(const half8*)(rbase + ar * DIM + lk);

    // build hp[j] for all 4096 cols (coalesced)
#pragma unroll
    for (int q = 0; q < 8; q++) {
        int j = t + q * ITHREADS;
        hps[j] = (hbase + fmaf(don, dual[j], -cn2[j]) * inv_eps) * L2E;
    }
    __syncthreads();

    // wave's column window: 64 cts of 16 cols; depth-4 rings for B and hp
    const short* cwb = cbase + (size_t)cwin * DIM;
    const int laneoff = lr * DIM + lk;
    const float* hpw = hps + cwin + lr;

    half8 bh[4];
    float hpv[4];
#pragma unroll
    for (int p = 0; p < 4; p++) {
        const int w = (p + S) & 63;
        bh[p]  = *(const half8*)(cwb + w * (16 * DIM) + laneoff);
        hpv[p] = hpw[w * 16];
    }

    float ms[4] = {-INFINITY, -INFINITY, -INFINITY, -INFINITY};
    float ss[4] = {0.f, 0.f, 0.f, 0.f};
    f32x4 ca[4];
    float hpr[4];

    for (int g = 0; g < 16; g++) {
#pragma unroll
        for (int sl = 0; sl < 4; sl++) {
            const int ct = g * 4 + sl;
            const half8 hB = bh[sl];
            f32x4 u = {0.f, 0.f, 0.f, 0.f};
            u = __builtin_amdgcn_mfma_f32_16x16x32_f16(a0, hB, u, 0, 0, 0);
            hpr[sl] = hpv[sl];
            // prefetch ct+4 (past ct=59 wraps to already-visited windows; unused)
            const int w = ((ct + 4) + S) & 63;
            bh[sl]  = *(const half8*)(cwb + w * (16 * DIM) + laneoff);
            hpv[sl] = hpw[w * 16];
            ca[sl] = u;
        }
#pragma unroll
        for (int r = 0; r < 4; r++) {
            const float v0 = fmaf(ca[0][r], ie2, hpr[0]);
            const float v1 = fmaf(ca[1][r], ie2, hpr[1]);
            const float v2 = fmaf(ca[2][r], ie2, hpr[2]);
            const float v3 = fmaf(ca[3][r], ie2, hpr[3]);
            const float gm = fmaxf(fmaxf(v0, v1), fmaxf(v2, v3));
            if (__any(gm > ms[r])) {
                const float nm = fmaxf(ms[r], gm);
                ss[r] = fmaf(ss[r], exp2fast(ms[r] - nm),
                             (exp2fast(v0 - nm) + exp2fast(v1 - nm)) +
                             (exp2fast(v2 - nm) + exp2fast(v3 - nm)));
                ms[r] = nm;
            } else {
                ss[r] += (exp2fast(v0 - ms[r]) + exp2fast(v1 - ms[r])) +
                         (exp2fast(v2 - ms[r]) + exp2fast(v3 - ms[r]));
            }
        }
    }

    // merge the 16 col-lanes (lane bits 0..3)
#pragma unroll
    for (int wm = 1; wm <= 8; wm <<= 1) {
#pragma unroll
        for (int r = 0; r < 4; r++) {
            float om = __shfl_xor(ms[r], wm, 64);
            float os = __shfl_xor(ss[r], wm, 64);
            float nm = fmaxf(ms[r], om);
            ss[r] = fmaf(ss[r], exp2fast(ms[r] - nm), os * exp2fast(om - nm));
            ms[r] = nm;
        }
    }
    if (lr == 0) {
        const int g4 = (lane >> 4) * 4;
#pragma unroll
        for (int r = 0; r < 4; r++)
            parts[wv][g4 + r] = make_float2(ms[r], ss[r]);
    }
    __syncthreads();
    // final: rows 0..15 from waves 0..3, rows 16..31 from waves 4..7
    if (t < 32) {
        const int half = t >> 4;
        const int rr   = t & 15;
        float2 p = parts[half * 4][rr];
        float m = p.x, s = p.y;
#pragma unroll
        for (int w2 = 1; w2 < 4; w2++) {
            float2 q = parts[half * 4 + w2][rr];
            float nm = fmaxf(m, q.x);
            s = fmaf(s, exp2fast(m - nm), q.y * exp2fast(q.x - nm));
            m = nm;
        }
        const float lse = LN2 * (m + log2fast(s));
        const int row = tile * 32 + t;
        const float ft = rn2[row] - eps * lse;
        out[row] = (mode == M_AVG) ? 0.5f * (oldout[row] + ft) : ft;
    }
}

// ---------------- final: mean(f_ba - f_aa) + mean(g_ab - g_bb)
__global__ void sink_reduce(const float* __restrict__ ws, float* __restrict__ outp)
{
    __shared__ float red[NTHREADS];
    const float* b = ws + WS_DUAL;   // parity 0 after 50 slots
    int t = threadIdx.x;
    float acc = 0.f;
    for (int i = t; i < NPTS; i += NTHREADS)
        acc += (b[i] - b[2 * NPTS + i]) + (b[NPTS + i] - b[3 * NPTS + i]);
    red[t] = acc;
    __syncthreads();
    for (int s = NTHREADS / 2; s > 0; s >>= 1) {
        if (t < s) red[t] += red[t + s];
        __syncthreads();
    }
    if (t == 0) outp[0] = red[0] * (1.0f / (float)NPTS);
}

extern "C" void kernel_launch(void* const* d_in, const int* in_sizes, int n_in,
                              void* d_out, int out_size, void* d_ws, size_t ws_size,
                              hipStream_t stream)
{
    const float* x = (const float*)d_in[0];
    const float* y = (const float*)d_in[1];
    float* ws  = (float*)d_ws;
    float* out = (float*)d_out;

    hipLaunchKernelGGL(sink_norms,  dim3(32),  dim3(NTHREADS), 0, stream, x, y, ws);
    hipLaunchKernelGGL(sink_prep,   dim3(128), dim3(NTHREADS), 0, stream, x, y,
                       (unsigned short*)(ws + WS_BF));
    hipLaunchKernelGGL(sink_minmax, dim3(64),  dim3(NTHREADS), 0, stream, x, y, ws);
    hipLaunchKernelGGL(sink_sched,  dim3(1),   dim3(NTHREADS), 0, stream, ws);
    for (int s = 0; s < MAXSLOTS; s++)
        hipLaunchKernelGGL(sink_iter, dim3(512), dim3(ITHREADS), 0, stream, ws, s);
    hipLaunchKernelGGL(sink_reduce, dim3(1), dim3(NTHREADS), 0, stream, ws, out);
}

// Round 8
// 887.787 us; speedup vs baseline: 1.1223x; 1.1189x over previous
//
#include <hip/hip_runtime.h>
#include <math.h>

#define NPTS 4096
#define DIM  32
#define MAXSLOTS 50
#define NTHREADS 256
#define ITHREADS 512
#define NELEM 131072      // 4096*32

// ws layout in floats
#define WS_N2X   0
#define WS_N2Y   4096
#define WS_PMIN  8192
#define WS_PMAX  10240
#define WS_EPS   12288
#define WS_MODE  12352
#define WS_DUAL  12416
#define DUALSZ   16384    // 4 arrays * 4096 (one parity buffer)
#define WS_BF    45184    // fp16 pack area: 2*131072 ushorts = 512 KB

// modes
#define M_SKIP   0
#define M_INIT   1
#define M_AVG    2
#define M_ASSIGN 3

typedef short   short8 __attribute__((ext_vector_type(8)));
typedef _Float16 half8 __attribute__((ext_vector_type(8)));
typedef float   f32x4  __attribute__((ext_vector_type(4)));

__device__ __forceinline__ float exp2fast(float a){
#if __has_builtin(__builtin_amdgcn_exp2f)
    return __builtin_amdgcn_exp2f(a);
#else
    return exp2f(a);
#endif
}
__device__ __forceinline__ float log2fast(float a){
#if __has_builtin(__builtin_amdgcn_logf)
    return __builtin_amdgcn_logf(a);
#else
    return log2f(a);
#endif
}

// ---------------- norms: 0.5*|row|^2 for x and y (exact fp32)
__global__ void sink_norms(const float* __restrict__ x, const float* __restrict__ y,
                           float* __restrict__ ws)
{
    int row = blockIdx.x * blockDim.x + threadIdx.x;   // 32 blocks * 256 = 8192
    const float* src = (row < NPTS) ? (x + (size_t)row * DIM)
                                    : (y + (size_t)(row - NPTS) * DIM);
    const float4* s4 = (const float4*)src;
    float acc = 0.f;
#pragma unroll
    for (int q = 0; q < 8; q++) {
        float4 v = s4[q];
        acc += v.x*v.x + v.y*v.y + v.z*v.z + v.w*v.w;
    }
    ws[row] = 0.5f * acc;
}

// ---------------- fp16 prepack: [xh | yh] row-major
__global__ void sink_prep(const float* __restrict__ x, const float* __restrict__ y,
                          unsigned short* __restrict__ bf)
{
    int tid = blockIdx.x * 256 + threadIdx.x;          // 32768 threads, 8 elems each
    int e = tid * 8;
    const float* src = (e < NELEM) ? (x + e) : (y + (e - NELEM));
    float4 v0 = ((const float4*)src)[0];
    float4 v1 = ((const float4*)src)[1];
    float vs[8] = {v0.x, v0.y, v0.z, v0.w, v1.x, v1.y, v1.z, v1.w};
    short hv[8];
#pragma unroll
    for (int i = 0; i < 8; i++) {
        union { _Float16 f; short s; } u;
        u.f = (_Float16)vs[i];           // RNE f32->f16
        hv[i] = u.s;
    }
    short8 hvec = {hv[0],hv[1],hv[2],hv[3],hv[4],hv[5],hv[6],hv[7]};
    *(short8*)((short*)bf + e) = hvec;   // x at [0,NELEM), y at [NELEM,2*NELEM)
}

// ---------------- per-dim min/max partials over concat(x,y)
__global__ void sink_minmax(const float* __restrict__ x, const float* __restrict__ y,
                            float* __restrict__ ws)
{
    __shared__ float2 mm[8][32];
    int t = threadIdx.x;
    int d = t & 31, rg = t >> 5;
    float mn = 3.4e38f, mx = -3.4e38f;
#pragma unroll
    for (int k = 0; k < 16; k++) {
        int row = blockIdx.x * 128 + k * 8 + rg;
        const float* src = (row < NPTS) ? (x + (size_t)row * DIM)
                                        : (y + (size_t)(row - NPTS) * DIM);
        float v = src[d];
        mn = fminf(mn, v); mx = fmaxf(mx, v);
    }
    mm[rg][d] = make_float2(mn, mx);
    __syncthreads();
    if (t < 32) {
        float2 a = mm[0][t];
#pragma unroll
        for (int g = 1; g < 8; g++) {
            float2 b = mm[g][t];
            a.x = fminf(a.x, b.x); a.y = fmaxf(a.y, b.y);
        }
        ws[WS_PMIN + blockIdx.x * 32 + t] = a.x;
        ws[WS_PMAX + blockIdx.x * 32 + t] = a.y;
    }
}

// ---------------- schedule: diameter -> eps list + mode per slot
__global__ void sink_sched(float* __restrict__ ws)
{
    __shared__ float mins[32], maxs[32];
    int t = threadIdx.x;
    if (t < 32) {
        float mn = 3.4e38f, mx = -3.4e38f;
        for (int b = 0; b < 64; b++) {
            mn = fminf(mn, ws[WS_PMIN + b * 32 + t]);
            mx = fmaxf(mx, ws[WS_PMAX + b * 32 + t]);
        }
        mins[t] = mn; maxs[t] = mx;
    }
    __syncthreads();
    if (t == 0) {
        float dia2 = 0.f;
        for (int d = 0; d < 32; d++) {
            float df = maxs[d] - mins[d];
            dia2 += df * df;
        }
        float dia = sqrtf(dia2);
        float* eps = ws + WS_EPS;
        int*  mode = (int*)(ws + WS_MODE);
        double ld    = log((double)dia);
        double start = 2.0 * ld;
        double stop  = 2.0 * log(0.5);
        double step  = 2.0 * log(0.9);
        int K = (int)ceil((stop - start) / step);
        if (K < 0) K = 0;
        if (K > MAXSLOTS - 5) K = MAXSLOTS - 5;
        eps[0] = dia * dia; mode[0] = M_INIT;
        eps[1] = dia * dia; mode[1] = M_AVG;
        for (int k = 0; k < K; k++) {
            eps[2 + k] = (float)exp(start + step * (double)k);
            mode[2 + k] = M_AVG;
        }
        eps[2 + K] = 0.25f; mode[2 + K] = M_AVG;
        eps[3 + K] = 0.25f; mode[3 + K] = M_ASSIGN;
        for (int s = 4 + K; s < MAXSLOTS; s++) { eps[s] = 0.25f; mode[s] = M_SKIP; }
    }
}

// grouped online-LSE over 4 accumulated cts, for tile T register R
#define GLSE(T, R) \
    { float v0 = fmaf(ca##T[0][R], ie2, hpr[0]); \
      float v1 = fmaf(ca##T[1][R], ie2, hpr[1]); \
      float v2 = fmaf(ca##T[2][R], ie2, hpr[2]); \
      float v3 = fmaf(ca##T[3][R], ie2, hpr[3]); \
      float gm = fmaxf(fmaxf(v0, v1), v2); \
      float nm = fmaxf(fmaxf(gm, v3), ms##T[R]); \
      float er = exp2fast(ms##T[R] - nm); \
      float e0 = exp2fast(v0 - nm); \
      float e1 = exp2fast(v1 - nm); \
      float e2 = exp2fast(v2 - nm); \
      float e3 = exp2fast(v3 - nm); \
      ss##T[R] = fmaf(ss##T[R], er, (e0 + e1) + (e2 + e3)); \
      ms##T[R] = nm; }

// ---------------- fused softmin iteration (single fp16 MFMA, depth-6 B/hp ring)
// grid = 4 matrices * 128 row-tiles(32 rows) = 512 blocks, 512 threads (8 waves)
// block: 32 rows (2 MFMA row-tiles per wave); wave w: cols [w*512,(w+1)*512)
// column sweep skewed per block to de-phase the shared B stream in L2
__global__ __launch_bounds__(ITHREADS, 4) void sink_iter(float* __restrict__ ws, int slot)
{
    const int t = threadIdx.x;
    const int mode = ((const int*)(ws + WS_MODE))[slot];

    if (mode == M_SKIP) {
        int idx = blockIdx.x * ITHREADS + t;
        if (idx < DUALSZ)
            ws[WS_DUAL + ((slot + 1) & 1) * DUALSZ + idx] =
                ws[WS_DUAL + (slot & 1) * DUALSZ + idx];
        return;
    }

    const float eps     = ws[WS_EPS + slot];
    const float inv_eps = 1.0f / eps;
    const float L2E     = 1.4426950408889634f;
    const float LN2     = 0.6931471805599453f;
    const float ie2     = inv_eps * L2E;
    const float hbase   = -8.317766166719343f;   // -ln(4096)
    const float don     = (mode == M_INIT) ? 0.0f : 1.0f;

    const int bm   = blockIdx.x >> 7;     // 0=xy 1=yx 2=xx 3=yy
    const int tile = blockIdx.x & 127;    // 32-row tile index
    const int S    = (blockIdx.x * 5) & 31;   // per-block sweep skew
    const int rowIsX = (bm == 0 || bm == 2);
    const int colIsX = (bm == 1 || bm == 2);

    const short* bf = (const short*)(ws + WS_BF);
    const short* rbase = bf + (rowIsX ? 0 : NELEM);
    const short* cbase = bf + (colIsX ? 0 : NELEM);
    const float* rn2 = ws + (rowIsX ? WS_N2X : WS_N2Y);
    const float* cn2 = ws + (colIsX ? WS_N2X : WS_N2Y);

    const float* bufold = ws + WS_DUAL + (slot & 1) * DUALSZ;
    float*       bufnew = ws + WS_DUAL + ((slot + 1) & 1) * DUALSZ;
    const int dualsel = (bm == 0) ? 1 : (bm == 1) ? 0 : bm;   // {1,0,2,3}
    const float* dual   = bufold + dualsel * NPTS;
    const float* oldout = bufold + bm * NPTS;
    float*       out    = bufnew + bm * NPTS;

    __shared__ float  hps[NPTS];          // 16 KB
    __shared__ float2 parts[8][32];       // 2 KB

    const int lane = t & 63;
    const int wv   = t >> 6;
    const int lr   = lane & 15;          // A-row / B-col within 16-tile
    const int lk   = (lane >> 4) * 8;    // k offset (8 contiguous fp16)

    // A fragments: two row-tiles (rows tile*32+lr and tile*32+16+lr)
    const int ar0 = tile * 32 + lr;
    const half8 a0 = *(const half8*)(rbase + ar0 * DIM + lk);
    const half8 a1 = *(const half8*)(rbase + (ar0 + 16) * DIM + lk);

    // build hp[j] for all 4096 cols (coalesced)
#pragma unroll
    for (int q = 0; q < 8; q++) {
        int j = t + q * ITHREADS;
        hps[j] = (hbase + fmaf(don, dual[j], -cn2[j]) * inv_eps) * L2E;
    }
    __syncthreads();

    // wave's column window; depth-6 ring for B fragments and hp
    const int colbase = wv * 512;
    const short* cwb = cbase + (size_t)colbase * DIM;
    const int laneoff = lr * DIM + lk;
    const float* hpw = hps + colbase + lr;

    half8 bh[6];
    float hpv[6];
#pragma unroll
    for (int p = 0; p < 6; p++) {
        const int w = (p + S) & 31;
        bh[p]  = *(const half8*)(cwb + w * (16 * DIM) + laneoff);
        hpv[p] = hpw[w * 16];
    }

    float ms0[4] = {-INFINITY, -INFINITY, -INFINITY, -INFINITY};
    float ms1[4] = {-INFINITY, -INFINITY, -INFINITY, -INFINITY};
    float ss0[4] = {0.f, 0.f, 0.f, 0.f};
    float ss1[4] = {0.f, 0.f, 0.f, 0.f};

    f32x4 ca0[4], ca1[4];
    float hpr[4];

#pragma unroll
    for (int ct = 0; ct < 32; ct++) {
        const int sl = ct % 6;           // ring slot (compile-time in unrolled loop)
        const half8 hB = bh[sl];
        hpr[ct & 3] = hpv[sl];
        f32x4 u0 = {0.f, 0.f, 0.f, 0.f};
        f32x4 u1 = {0.f, 0.f, 0.f, 0.f};
        u0 = __builtin_amdgcn_mfma_f32_16x16x32_f16(a0, hB, u0, 0, 0, 0);
        u1 = __builtin_amdgcn_mfma_f32_16x16x32_f16(a1, hB, u1, 0, 0, 0);
        if (ct < 26) {
            const int w = ((ct + 6) + S) & 31;
            bh[sl]  = *(const half8*)(cwb + w * (16 * DIM) + laneoff);
            hpv[sl] = hpw[w * 16];
        }
        ca0[ct & 3] = u0;
        ca1[ct & 3] = u1;
        if ((ct & 3) == 3) {
            GLSE(0, 0) GLSE(0, 1) GLSE(0, 2) GLSE(0, 3)
            GLSE(1, 0) GLSE(1, 1) GLSE(1, 2) GLSE(1, 3)
        }
    }

    // merge the 16 col-lanes (lane bits 0..3)
#pragma unroll
    for (int wm = 1; wm <= 8; wm <<= 1) {
#pragma unroll
        for (int r = 0; r < 4; r++) {
            float om, os, nm;
            om = __shfl_xor(ms0[r], wm, 64); os = __shfl_xor(ss0[r], wm, 64);
            nm = fmaxf(ms0[r], om);
            ss0[r] = fmaf(ss0[r], exp2fast(ms0[r] - nm), os * exp2fast(om - nm));
            ms0[r] = nm;
            om = __shfl_xor(ms1[r], wm, 64); os = __shfl_xor(ss1[r], wm, 64);
            nm = fmaxf(ms1[r], om);
            ss1[r] = fmaf(ss1[r], exp2fast(ms1[r] - nm), os * exp2fast(om - nm));
            ms1[r] = nm;
        }
    }
    if (lr == 0) {
        const int g4 = (lane >> 4) * 4;
#pragma unroll
        for (int r = 0; r < 4; r++) {
            parts[wv][g4 + r]      = make_float2(ms0[r], ss0[r]);
            parts[wv][16 + g4 + r] = make_float2(ms1[r], ss1[r]);
        }
    }
    __syncthreads();
    if (t < 32) {
        float2 p = parts[0][t];
        float m = p.x, s = p.y;
#pragma unroll
        for (int w2 = 1; w2 < 8; w2++) {
            float2 q = parts[w2][t];
            float nm = fmaxf(m, q.x);
            s = fmaf(s, exp2fast(m - nm), q.y * exp2fast(q.x - nm));
            m = nm;
        }
        const float lse = LN2 * (m + log2fast(s));
        const int row = tile * 32 + t;
        const float ft = rn2[row] - eps * lse;
        out[row] = (mode == M_AVG) ? 0.5f * (oldout[row] + ft) : ft;
    }
}

// ---------------- final: mean(f_ba - f_aa) + mean(g_ab - g_bb)
__global__ void sink_reduce(const float* __restrict__ ws, float* __restrict__ outp)
{
    __shared__ float red[NTHREADS];
    const float* b = ws + WS_DUAL;   // parity 0 after 50 slots
    int t = threadIdx.x;
    float acc = 0.f;
    for (int i = t; i < NPTS; i += NTHREADS)
        acc += (b[i] - b[2 * NPTS + i]) + (b[NPTS + i] - b[3 * NPTS + i]);
    red[t] = acc;
    __syncthreads();
    for (int s = NTHREADS / 2; s > 0; s >>= 1) {
        if (t < s) red[t] += red[t + s];
        __syncthreads();
    }
    if (t == 0) outp[0] = red[0] * (1.0f / (float)NPTS);
}

extern "C" void kernel_launch(void* const* d_in, const int* in_sizes, int n_in,
                              void* d_out, int out_size, void* d_ws, size_t ws_size,
                              hipStream_t stream)
{
    const float* x = (const float*)d_in[0];
    const float* y = (const float*)d_in[1];
    float* ws  = (float*)d_ws;
    float* out = (float*)d_out;

    hipLaunchKernelGGL(sink_norms,  dim3(32),  dim3(NTHREADS), 0, stream, x, y, ws);
    hipLaunchKernelGGL(sink_prep,   dim3(128), dim3(NTHREADS), 0, stream, x, y,
                       (unsigned short*)(ws + WS_BF));
    hipLaunchKernelGGL(sink_minmax, dim3(64),  dim3(NTHREADS), 0, stream, x, y, ws);
    hipLaunchKernelGGL(sink_sched,  dim3(1),   dim3(NTHREADS), 0, stream, ws);
    for (int s = 0; s < MAXSLOTS; s++)
        hipLaunchKernelGGL(sink_iter, dim3(512), dim3(ITHREADS), 0, stream, ws, s);
    hipLaunchKernelGGL(sink_reduce, dim3(1), dim3(NTHREADS), 0, stream, ws, out);
}